// Round 14
// baseline (229.317 us; speedup 1.0000x reference)
//
#include <hip/hip_runtime.h>
#include <math.h>

#define KEHALF_F 7.199822675975274f   // 14.399645351950548 / 2
#define A_ATOMS 1024
#define LOG2E_F 1.4426950408889634f
#define LN2_F   0.6931471805599453f
#define NISS    5                     // staging issues per array: covers 1026..1280 elems
#define ABYTES  (NISS * 1024)         // 5120 B per array per row buffer
#define ROWS_PER_WAVE 16

#if !__has_builtin(__builtin_amdgcn_exp2f)
extern "C" __device__ float __ocml_native_exp2_f32(float);
#endif
#if !__has_builtin(__builtin_amdgcn_logf)
extern "C" __device__ float __ocml_native_log2_f32(float);
#endif

__device__ __forceinline__ float fast_exp2(float x) {   // v_exp_f32
#if __has_builtin(__builtin_amdgcn_exp2f)
    return __builtin_amdgcn_exp2f(x);
#else
    return __ocml_native_exp2_f32(x);
#endif
}
__device__ __forceinline__ float fast_log2(float x) {   // v_log_f32
#if __has_builtin(__builtin_amdgcn_logf)
    return __builtin_amdgcn_logf(x);
#else
    return __ocml_native_log2_f32(x);
#endif
}
__device__ __forceinline__ float fast_rcp(float x) {    // v_rcp_f32
#if __has_builtin(__builtin_amdgcn_rcpf)
    return __builtin_amdgcn_rcpf(x);
#else
    return __frcp_rn(x);
#endif
}
__device__ __forceinline__ float softplus_f(float x) {
    return LN2_F * fast_log2(1.0f + fast_exp2(x * LOG2E_F));
}

// async global->LDS, 16B per lane; dest = uniform base + lane*16 (HW rule)
__device__ __forceinline__ void gload_lds16(const void* g, void* l) {
    __builtin_amdgcn_global_load_lds(
        (const __attribute__((address_space(1))) void*)g,
        (__attribute__((address_space(3))) void*)l,
        16, 0, 0);
}

// Prekernel: tab[i] = (Zf, Zf^sp(apow) * sp(adiv))
__global__ __launch_bounds__(256) void zbl_pre_kernel(
    const int* __restrict__ atomic_numbers,
    const float* __restrict__ p_adiv, const float* __restrict__ p_apow,
    float2* __restrict__ tab, int n)
{
    const int i = blockIdx.x * 256 + threadIdx.x;
    if (i < n) {
        const float sp_apow = softplus_f(p_apow[0]);
        const float sp_adiv = softplus_f(p_adiv[0]);
        float zf = (float)atomic_numbers[i];
        tab[i] = make_float2(zf, fast_exp2(sp_apow * fast_log2(zf)) * sp_adiv);
    }
}

// Stage one row's nb/mk/rr into a wave-private LDS buffer: 15 fire-and-forget
// global_load_lds issues (no VGPR dest -> compiler cannot sink them).
// Sources staged from 4-element-aligned covering range; clamped to Ntot-4.
__device__ __forceinline__ void stage_row(
    int row, char* lb,
    const int* __restrict__ nb, const float* __restrict__ mk,
    const float* __restrict__ rr, int K, int Ntot, int lane)
{
    const int base = row * K;
    const int al   = base & ~3;
    const int cap  = Ntot - 4;
    #pragma unroll
    for (int i = 0; i < NISS; ++i) {
        int e = al + (i << 8) + (lane << 2);
        if (e > cap) e = cap;                    // stay inside the arrays
        gload_lds16(nb + e, lb + 0 * ABYTES + (i << 10));
        gload_lds16(mk + e, lb + 1 * ABYTES + (i << 10));
        gload_lds16(rr + e, lb + 2 * ABYTES + (i << 10));
    }
}

// Main: 512 blocks x 128 threads (2 waves). 2 blocks/CU (LDS 69.8KB).
// Each wave: 16 consecutive rows, double-buffered LDS row staging via
// global_load_lds, counted vmcnt(15) waits (never a barrier in the loop).
__global__ __launch_bounds__(128) void zbl_main_kernel(
    const int* __restrict__ neighbors,
    const float* __restrict__ neighbor_mask,
    const float* __restrict__ r_ij,
    const float2* __restrict__ tab,
    const float* __restrict__ p_c1, const float* __restrict__ p_c2,
    const float* __restrict__ p_c3, const float* __restrict__ p_c4,
    const float* __restrict__ p_a1, const float* __restrict__ p_a2,
    const float* __restrict__ p_a3, const float* __restrict__ p_a4,
    float* __restrict__ out, int K, int Ntot)
{
    __shared__ float2 zz[A_ATOMS];                 // 8 KB per block
    __shared__ char   stg[2][2][3][ABYTES];        // [wave][buf][array] 60 KB
    __shared__ float  res[2 * ROWS_PER_WAVE];      // per-wave row results

    const int tid  = threadIdx.x;
    const int wid  = tid >> 6;
    const int lane = tid & 63;

    // uniform params first (SMEM loads; ordered before staging issues)
    float c1 = softplus_f(p_c1[0]), c2 = softplus_f(p_c2[0]);
    float c3 = softplus_f(p_c3[0]), c4 = softplus_f(p_c4[0]);
    const float inv_cs = 1.0f / (c1 + c2 + c3 + c4);
    c1 *= inv_cs; c2 *= inv_cs; c3 *= inv_cs; c4 *= inv_cs;
    const float b1 = -softplus_f(p_a1[0]) * LOG2E_F;
    const float b2 = -softplus_f(p_a2[0]) * LOG2E_F;
    const float b3 = -softplus_f(p_a3[0]) * LOG2E_F;
    const float b4 = -softplus_f(p_a4[0]) * LOG2E_F;

    // stage per-batch zz table (8 KB, plain vector copy), one barrier total
    const int bidx = blockIdx.x >> 5;              // 32 rows/block, 1024/batch
    {
        const float4* ts = (const float4*)(tab + ((size_t)bidx << 10));
        float4* zd = (float4*)zz;
        #pragma unroll
        for (int t = 0; t < 4; ++t) zd[tid + (t << 7)] = ts[tid + (t << 7)];
    }
    __syncthreads();

    const int wrow0 = (blockIdx.x * 2 + wid) << 4; // 16 rows per wave
    char* my_stg0 = &stg[wid][0][0][0];
    char* my_stg1 = &stg[wid][1][0][0];

    // prologue: fill both buffers (30 issues in flight = 30 KB/wave)
    stage_row(wrow0 + 0, my_stg0, neighbors, neighbor_mask, r_ij, K, Ntot, lane);
    stage_row(wrow0 + 1, my_stg1, neighbors, neighbor_mask, r_ij, K, Ntot, lane);

    for (int r = 0; r < ROWS_PER_WAVE; ++r) {
        // counted drain: oldest 15 (= row r's issues) complete; row r+1 stays in flight
        if (r < ROWS_PER_WAVE - 1) {
            asm volatile("s_waitcnt vmcnt(15)" ::: "memory");
        } else {
            asm volatile("s_waitcnt vmcnt(0)" ::: "memory");
        }
        __builtin_amdgcn_sched_barrier(0);

        const int row  = wrow0 + r;
        const int off  = (row * K) & 3;            // covering-range offset
        const int bsel = r & 1;
        const int*   nbp = (const int*)  &stg[wid][bsel][0][0];
        const float* mkp = (const float*)&stg[wid][bsel][1][0];
        const float* rrp = (const float*)&stg[wid][bsel][2][0];

        const float2 zi = zz[row & (A_ATOMS - 1)];
        const float zix = KEHALF_F * zi.x;
        const float ziy = zi.y;

        float accA = 0.0f, accB = 0.0f;
        #pragma unroll
        for (int i = 0; i < 16; ++i) {
            const int e = lane + (i << 6);         // element index in row
            const int s = off + e;                 // LDS slot
            int   j  = nbp[s];
            float m  = mkp[s];
            float rv = rrp[s];
            if (e >= K) m = 0.0f;                  // only lane63 @ i=15 for K=1023
            float2 zj = zz[j];
            float ar = (ziy + zj.y) * rv;          // mask NOT in exponent
            float fe = c1 * fast_exp2(b1 * ar) + c2 * fast_exp2(b2 * ar)
                     + c3 * fast_exp2(b3 * ar) + c4 * fast_exp2(b4 * ar);
            float t = fe * (zix * zj.x * m) * fast_rcp(rv);
            if (i & 1) accB += t; else accA += t;
        }
        float acc = accA + accB;
        #pragma unroll
        for (int o = 32; o > 0; o >>= 1)
            acc += __shfl_down(acc, o, 64);
        if (lane == 0) res[(wid << 4) + r] = acc;  // LDS, not vmcnt

        // refill the buffer we just consumed with row r+2
        if (r + 2 < ROWS_PER_WAVE)
            stage_row(wrow0 + r + 2, bsel ? my_stg1 : my_stg0,
                      neighbors, neighbor_mask, r_ij, K, Ntot, lane);
    }

    // one coalesced 64B store per wave
    if (lane < ROWS_PER_WAVE)
        out[wrow0 + lane] = res[(wid << 4) + lane];
}

extern "C" void kernel_launch(void* const* d_in, const int* in_sizes, int n_in,
                              void* d_out, int out_size, void* d_ws, size_t ws_size,
                              hipStream_t stream) {
    const int*   neighbors      = (const int*)  d_in[0];
    const float* neighbor_mask  = (const float*)d_in[1];
    const int*   atomic_numbers = (const int*)  d_in[2];
    const float* r_ij           = (const float*)d_in[3];

    float*  out = (float*)d_out;
    float2* tab = (float2*)d_ws;

    const int n = in_sizes[2];          // B*A = 16384
    const int K = in_sizes[0] / n;      // 1023
    const int Ntot = n * K;

    zbl_pre_kernel<<<(n + 255) / 256, 256, 0, stream>>>(
        atomic_numbers, (const float*)d_in[4], (const float*)d_in[5], tab, n);

    const int nwaves = n / ROWS_PER_WAVE;          // 1024
    zbl_main_kernel<<<nwaves / 2, 128, 0, stream>>>(
        neighbors, neighbor_mask, r_ij, tab,
        (const float*)d_in[6], (const float*)d_in[7],
        (const float*)d_in[8], (const float*)d_in[9],
        (const float*)d_in[10], (const float*)d_in[11],
        (const float*)d_in[12], (const float*)d_in[13],
        out, K, Ntot);
}